// Round 8
// baseline (187.725 us; speedup 1.0000x reference)
//
#include <hip/hip_runtime.h>
#include <hip/hip_bf16.h>
#include <math.h>

#define CC 256
#define NN 4096

typedef __bf16 bf16x8 __attribute__((ext_vector_type(8)));
typedef __bf16 bf16x4 __attribute__((ext_vector_type(4)));
typedef float  f32x4  __attribute__((ext_vector_type(4)));

#define MFMA16x16x32 __builtin_amdgcn_mfma_f32_16x16x32_bf16

__device__ inline float exp2_hw(float x) {
    float r;
    asm("v_exp_f32 %0, %1" : "=v"(r) : "v"(x));
    return r;
}

// key permutation within a 32-key group: j = 16*jhi + 4*g + r -> 8*g + 4*jhi + r
// (one bf16x8 P write per lane per 32-key half; V2 k-dim uses the same order)
__device__ inline int kperm(int j) {
    return ((j & 12) << 1) | ((j & 16) >> 2) | (j & 3);
}

// ---------------------------------------------------------------------------
// wprep: W_all = concat(qw*log2e, kw, vw) -> Wh,Wl bf16 [320][256] (split
// x ~= hi + lo), biasF f32[320]. log2e folded into q so softmax is 2^x.
// ---------------------------------------------------------------------------
__global__ void wprep_kernel(
    const float* __restrict__ qw, const float* __restrict__ qb,
    const float* __restrict__ kw, const float* __restrict__ kb,
    const float* __restrict__ vw, const float* __restrict__ vb,
    __bf16* __restrict__ Wh, __bf16* __restrict__ Wl, float* __restrict__ biasF)
{
    const int r = blockIdx.x;
    const int c = threadIdx.x;
    const float L2E = 1.4426950408889634f;
    const float* wsrc; const float* bsrc; int r0; float scale;
    if (r < 32)       { wsrc = qw; bsrc = qb; r0 = r;      scale = L2E; }
    else if (r < 64)  { wsrc = kw; bsrc = kb; r0 = r - 32; scale = 1.f; }
    else              { wsrc = vw; bsrc = vb; r0 = r - 64; scale = 1.f; }
    float v = wsrc[(size_t)r0 * CC + c] * scale;
    __bf16 hi = (__bf16)v;
    Wh[(size_t)r * CC + c] = hi;
    Wl[(size_t)r * CC + c] = (__bf16)(v - (float)hi);
    if (c == 0) biasF[r] = bsrc[r0] * scale;
}

// ---------------------------------------------------------------------------
// proj_kernel: fused transpose/split/GEMM. Per block: 64 n-cols x 160 W rows
// (row-half rh). x f32 staged via LDS, split to bf16 hi/lo [n][c] tiles,
// split-bf16 3-MFMA (WhXh + WhXl + WlXh) with W rows from L2.
// 8 waves: wave w -> n-tile (w&3), row-tile parity (w>>2); 5 row-tiles each.
// Grid (64 ntiles, 2 rowhalf, 4 b) = 512 blocks -> 2 blocks/CU so one
// block's MFMA phase hides the other's staging barriers.
// Writes Qb,Kb bf16 [b][n][32]; V2 bf16 [b][n/32][c][32] with kperm'd k-dim.
// ---------------------------------------------------------------------------
__global__ __launch_bounds__(512) void proj_kernel(
    const float* __restrict__ x,
    const __bf16* __restrict__ Wh, const __bf16* __restrict__ Wl,
    const float* __restrict__ biasF,
    __bf16* __restrict__ Qb, __bf16* __restrict__ Kb, __bf16* __restrict__ V2)
{
    const int t    = threadIdx.x;
    const int w    = t >> 6;
    const int lane = t & 63;
    const int lrow = lane & 15;
    const int lgrp = lane >> 4;
    const int n0   = blockIdx.x * 64;
    const int rh   = blockIdx.y;          // row half: rows rh*160 .. +159
    const int b    = blockIdx.z;
    const int nt   = w & 3;
    const int rp   = w >> 2;

    __shared__ float  xs[64][68];
    __shared__ __bf16 xbh[64][136];
    __shared__ __bf16 xbl[64][136];

    f32x4 acc[5];
    #pragma unroll
    for (int i = 0; i < 5; ++i) acc[i] = f32x4{0.f, 0.f, 0.f, 0.f};

    for (int ch = 0; ch < 2; ++ch) {
        for (int cc = 0; cc < 2; ++cc) {
            __syncthreads();              // guards xs & xb from previous readers
            {   // stage xs[c'][n'] = x[b][ch*128+cc*64+c'][n0+n'] (coalesced)
                const float* xg = x + ((size_t)b * CC + ch * 128 + cc * 64) * NN + n0;
                const int row = t >> 3;
                const int col = (t & 7) * 8;
                float4 a0 = *(const float4*)&xg[(size_t)row * NN + col];
                float4 a1 = *(const float4*)&xg[(size_t)row * NN + col + 4];
                *(float4*)&xs[row][col]     = a0;
                *(float4*)&xs[row][col + 4] = a1;
            }
            __syncthreads();
            {   // transpose + split -> xb[n][c] hi/lo
                const int cn = t & 63;
                const int cg = t >> 6;
                bf16x8 h, l;
                #pragma unroll
                for (int e = 0; e < 8; ++e) {
                    float v = xs[cg * 8 + e][cn];
                    __bf16 hi = (__bf16)v;
                    h[e] = hi; l[e] = (__bf16)(v - (float)hi);
                }
                *(bf16x8*)&xbh[cn][cc * 64 + cg * 8] = h;
                *(bf16x8*)&xbl[cn][cc * 64 + cg * 8] = l;
            }
        }
        __syncthreads();                  // xb tiles complete for this half

        #pragma unroll
        for (int ks = 0; ks < 4; ++ks) {
            const bf16x8 bh = *(const bf16x8*)&xbh[nt * 16 + lrow][ks * 32 + lgrp * 8];
            const bf16x8 bl = *(const bf16x8*)&xbl[nt * 16 + lrow][ks * 32 + lgrp * 8];
            #pragma unroll
            for (int i = 0; i < 5; ++i) {
                const int rt = rp + 2 * i;
                const size_t ao = (size_t)(rh * 160 + rt * 16 + lrow) * CC + ch * 128 + ks * 32 + lgrp * 8;
                const bf16x8 ah = *(const bf16x8*)&Wh[ao];
                const bf16x8 al = *(const bf16x8*)&Wl[ao];
                acc[i] = MFMA16x16x32(ah, bh, acc[i], 0, 0, 0);
                acc[i] = MFMA16x16x32(ah, bl, acc[i], 0, 0, 0);
                acc[i] = MFMA16x16x32(al, bh, acc[i], 0, 0, 0);
            }
        }
    }

    // epilogue: C-frag col = n (lane&15), row = rh*160 + rt*16 + lgrp*4 + r
    const int n = n0 + nt * 16 + lrow;
    #pragma unroll
    for (int i = 0; i < 5; ++i) {
        const int rt = rp + 2 * i;
        const int g0 = rh * 160 + rt * 16 + lgrp * 4;
        const float4 b4 = *(const float4*)&biasF[g0];
        const float v0 = acc[i].x + b4.x, v1 = acc[i].y + b4.y;
        const float v2 = acc[i].z + b4.z, v3 = acc[i].w + b4.w;
        if (g0 < 32) {
            bf16x4 o = { (__bf16)v0, (__bf16)v1, (__bf16)v2, (__bf16)v3 };
            *(bf16x4*)&Qb[((size_t)b * NN + n) * 32 + g0] = o;
        } else if (g0 < 64) {
            bf16x4 o = { (__bf16)v0, (__bf16)v1, (__bf16)v2, (__bf16)v3 };
            *(bf16x4*)&Kb[((size_t)b * NN + n) * 32 + (g0 - 32)] = o;
        } else {
            const int c = g0 - 64;
            const size_t base = ((size_t)b * 128 + (n >> 5)) * (CC * 32) + kperm(n & 31);
            V2[base + (size_t)(c + 0) * 32] = (__bf16)v0;
            V2[base + (size_t)(c + 1) * 32] = (__bf16)v1;
            V2[base + (size_t)(c + 2) * 32] = (__bf16)v2;
            V2[base + (size_t)(c + 3) * 32] = (__bf16)v3;
        }
    }
}

// ---------------------------------------------------------------------------
// attn_kernel: flash attention + residual, no-max softmax (round-5 proven
// sync skeleton: write P -> lgkmcnt-only barrier -> read P, double-buffered
// by jt&1, one barrier/chunk, K/V prefetch spans the barrier).
// Block = 8 waves = 64 q x 128 ch (ch-half hh). Wave w = (qg=w>>1, kh=w&1)
// for QK (no in-block QK duplication); PV channels hh*128 + w*16.
// Grid 512 = (4b x 2hh x 64qt) -> TWO blocks per CU whose phases drift, so
// one block's QK/exp (VALU/TRANS) overlaps the other's PV (MFMA).
// (b,hh) pinned per XCD: per-XCD L2 set = K(b) 256KB + V-half 1MB.
// ---------------------------------------------------------------------------
__global__ __launch_bounds__(512, 4) void attn_kernel(
    const __bf16* __restrict__ Qb, const __bf16* __restrict__ Kb,
    const __bf16* __restrict__ V2,
    const float* __restrict__ x, const float* __restrict__ gamma,
    float* __restrict__ y)
{
    const int bid  = blockIdx.x;
    const int xcd  = bid & 7;
    const int b    = xcd >> 1;
    const int hh   = xcd & 1;
    const int qt   = bid >> 3;           // 0..63
    const int w    = threadIdx.x >> 6;
    const int lane = threadIdx.x & 63;
    const int lrow = lane & 15;
    const int lgrp = lane >> 4;
    const int qg   = w >> 1;             // q-group 0..3
    const int kh   = w & 1;              // key half 0..1
    const int c0w  = hh * 128 + w * 16;  // PV channel slice (16 ch/wave)

    __shared__ __align__(16) __bf16 P[2][64][64];   // 16 KB double buffer
    __shared__ float lsumP[64][2];

    const __bf16* Qbb = Qb + (size_t)b * NN * 32;
    const __bf16* Kbb = Kb + (size_t)b * NN * 32;
    const __bf16* Vbb = V2 + (size_t)b * 128 * 8192;

    // Q B-frag: col = q = lrow, k = d = lgrp*8+e
    const bf16x8 qf = *(const bf16x8*)&Qbb[(size_t)(qt * 64 + qg * 16 + lrow) * 32 + lgrp * 8];

    const size_t koff0 = (size_t)(kh * 32 + lrow) * 32 + lgrp * 8;
    const size_t koff1 = koff0 + 512;                 // +16 keys
    const size_t voff0 = (size_t)(c0w + lrow) * 32 + lgrp * 8;   // key-group 2jt
    const size_t voff1 = voff0 + 8192;                            // key-group 2jt+1

    f32x4 O[4];
    #pragma unroll
    for (int g2 = 0; g2 < 4; ++g2) O[g2] = f32x4{0.f, 0.f, 0.f, 0.f};
    float lsum_l = 0.f;
    const f32x4 zf = f32x4{0.f, 0.f, 0.f, 0.f};

    const int swz  = 16 * (lrow & 7);
    char* prowW    = (char*)&P[0][qg * 16 + lrow][0];
    const int woff = (kh * 64 + 16 * lgrp) ^ swz;

    bf16x8 kf0 = *(const bf16x8*)&Kbb[koff0];
    bf16x8 kf1 = *(const bf16x8*)&Kbb[koff1];

    for (int jt = 0; jt < 64; ++jt) {
        // current-chunk V + next-chunk K issued early; barrier below leaves
        // vmcnt outstanding so these span it.
        const size_t vrow = (size_t)(2 * jt) * 8192;
        const bf16x8 vf0 = *(const bf16x8*)&Vbb[vrow + voff0];
        const bf16x8 vf1 = *(const bf16x8*)&Vbb[vrow + voff1];
        const size_t jn = (size_t)((jt + 1) & 63) * 2048;
        const bf16x8 kn0 = *(const bf16x8*)&Kbb[jn + koff0];
        const bf16x8 kn1 = *(const bf16x8*)&Kbb[jn + koff1];

        // QK^T swapped: S[key][q]; key = kh*32 + 16*jhi + 4*lgrp + r, q = lrow
        const f32x4 s0 = MFMA16x16x32(kf0, qf, zf, 0, 0, 0);
        const f32x4 s1 = MFMA16x16x32(kf1, qf, zf, 0, 0, 0);

        float ps = 0.f;
        bf16x8 pk;
        #pragma unroll
        for (int r = 0; r < 4; ++r) { float e = exp2_hw(s0[r]); ps += e; pk[r]     = (__bf16)e; }
        #pragma unroll
        for (int r = 0; r < 4; ++r) { float e = exp2_hw(s1[r]); ps += e; pk[4 + r] = (__bf16)e; }
        lsum_l += ps;

        const int buf = jt & 1;
        *(bf16x8*)(prowW + buf * 8192 + woff) = pk;   // one ds_write_b128

        // barrier WITHOUT vmcnt drain (LDS visibility only)
        asm volatile("s_waitcnt lgkmcnt(0)\n\ts_barrier" ::: "memory");

        // PV: O[c][q] += V[c][k] * P[q][k]  (k in kperm order on both sides)
        #pragma unroll
        for (int g2 = 0; g2 < 4; ++g2) {
            const char* pr = (const char*)&P[buf][g2 * 16 + lrow][0];
            const bf16x8 pb0 = *(const bf16x8*)(pr + ((16 * lgrp) ^ swz));
            const bf16x8 pb1 = *(const bf16x8*)(pr + ((64 + 16 * lgrp) ^ swz));
            O[g2] = MFMA16x16x32(vf0, pb0, O[g2], 0, 0, 0);
            O[g2] = MFMA16x16x32(vf1, pb1, O[g2], 0, 0, 0);
        }
        kf0 = kn0; kf1 = kn1;
    }

    // lsum: fold the 4 lane-group copies, then combine kh halves via LDS
    lsum_l += __shfl_xor(lsum_l, 16);
    lsum_l += __shfl_xor(lsum_l, 32);
    if (lgrp == 0) lsumP[qg * 16 + lrow][kh] = lsum_l;
    __syncthreads();

    const float gm = gamma[0];
    #pragma unroll
    for (int g2 = 0; g2 < 4; ++g2) {
        const int q = qt * 64 + g2 * 16 + lrow;
        const float rinv = 1.f / (lsumP[g2 * 16 + lrow][0] + lsumP[g2 * 16 + lrow][1]);
        #pragma unroll
        for (int r = 0; r < 4; ++r) {
            const int c = c0w + lgrp * 4 + r;
            const size_t idx = ((size_t)b * CC + c) * NN + q;
            y[idx] = x[idx] + gm * O[g2][r] * rinv;
        }
    }
}

// ---------------------------------------------------------------------------
extern "C" void kernel_launch(void* const* d_in, const int* in_sizes, int n_in,
                              void* d_out, int out_size, void* d_ws, size_t ws_size,
                              hipStream_t stream)
{
    const float* x     = (const float*)d_in[0];
    const float* qw    = (const float*)d_in[1];
    const float* qb    = (const float*)d_in[2];
    const float* kw    = (const float*)d_in[3];
    const float* kb    = (const float*)d_in[4];
    const float* vw    = (const float*)d_in[5];
    const float* vb    = (const float*)d_in[6];
    const float* gamma = (const float*)d_in[7];
    float* y = (float*)d_out;

    char* ws = (char*)d_ws;
    __bf16* Wh    = (__bf16*)(ws);                     // 160 KB [320][256]
    __bf16* Wl    = (__bf16*)(ws + 163840);            // 160 KB
    float*  biasF = (float*) (ws + 327680);            // 1.25 KB
    __bf16* Qb    = (__bf16*)(ws + 1048576);           // 1 MB [4][4096][32]
    __bf16* Kb    = (__bf16*)(ws + 2097152);           // 1 MB
    __bf16* V2    = (__bf16*)(ws + 3145728);           // 8 MB [4][128][256][32]

    hipLaunchKernelGGL(wprep_kernel, dim3(320), dim3(256), 0, stream,
                       qw, qb, kw, kb, vw, vb, Wh, Wl, biasF);
    hipLaunchKernelGGL(proj_kernel, dim3(64, 2, 4), dim3(512), 0, stream,
                       x, Wh, Wl, biasF, Qb, Kb, V2);
    hipLaunchKernelGGL(attn_kernel, dim3(512), dim3(512), 0, stream,
                       Qb, Kb, V2, x, gamma, y);
}